// Round 11
// baseline (3908.942 us; speedup 1.0000x reference)
//
#include <hip/hip_runtime.h>
#include <hip/hip_bf16.h>
#include <math.h>

// Problem constants
#define B 32
#define N 128
#define BT (B*N)          // 4096
#define WD 100
#define UD 25
#define D 125             // LSTM hidden per direction
#define G4 (4*D)          // 500 gates
#define H2 (2*D)          // 250
#define HID 100
#define L 50

// Fast, overflow-safe activations on v_exp_f32
__device__ __forceinline__ float fast_tanh(float x) {
    float e = __expf(2.0f * x);
    return 1.0f - 2.0f / (e + 1.0f);
}
__device__ __forceinline__ float fast_sigmoid(float x) {
    return 1.0f / (1.0f + __expf(-x));
}
__device__ __forceinline__ float bcast_lane(float v, int k) {
    return __builtin_bit_cast(float, __builtin_amdgcn_readlane(__builtin_bit_cast(int, v), k));
}

// ---------------------------------------------------------------------------
// K0a: combined-bias setup (b_l0[1000], b_l1[1000], b_s3[300])
// ---------------------------------------------------------------------------
__global__ void bias_setup(const float* __restrict__ l0f_b, const float* __restrict__ l0b_b,
                           const float* __restrict__ l1f_b, const float* __restrict__ l1b_b,
                           const float* __restrict__ eh_b, const float* __restrict__ em_b,
                           const float* __restrict__ lm_b,
                           float* __restrict__ b_l0, float* __restrict__ b_l1,
                           float* __restrict__ b_s3) {
    int t = blockIdx.x * blockDim.x + threadIdx.x;
    if (t < 500)        b_l0[t] = l0f_b[t];
    else if (t < 1000)  b_l0[t] = l0b_b[t-500];
    else if (t < 1500)  b_l1[t-1000] = l1f_b[t-1000];
    else if (t < 2000)  b_l1[t-1000] = l1b_b[t-1500];
    else if (t < 2100)  b_s3[t-2000] = eh_b[t-2000];
    else if (t < 2200)  b_s3[t-2000] = em_b[t-2100];
    else if (t < 2300)  b_s3[t-2000] = lm_b[t-2200];
}

// K0c: zero the pad rows (125..128) of the 4 WhT buffers
__global__ void pad_zero(float* __restrict__ w0, float* __restrict__ w1,
                         float* __restrict__ w2, float* __restrict__ w3) {
    int t = blockIdx.x * blockDim.x + threadIdx.x;   // 4 * 1516 = 6064 elems
    int m = t / 1516, e = t % 1516;
    float* p = (m == 0) ? w0 : (m == 1) ? w1 : (m == 2) ? w2 : w3;
    p[125*500 + e] = 0.0f;                           // covers 125*500 .. 128*500+16
}

// ---------------------------------------------------------------------------
// K0b: fused LDS-tiled transpose. out[k*ldo + coff + n] = in[n*C + k].
// ---------------------------------------------------------------------------
struct TJob { const float* src; float* dst; int R, C, ldo, coff, tile0, tiles_x; };
struct TArgs { TJob j[12]; };

__global__ __launch_bounds__(256)
void transpose_fused(TArgs a) {
    int bid = blockIdx.x;
    int ji = 0;
    #pragma unroll
    for (int i = 1; i < 12; i++) if (bid >= a.j[i].tile0) ji = i;
    TJob jb = a.j[ji];
    int t = bid - jb.tile0;
    int tx = t % jb.tiles_x;        // tile along C (k)
    int ty = t / jb.tiles_x;        // tile along R (n)
    __shared__ float tile[32][33];
    int k0 = tx*32, n0 = ty*32;
    #pragma unroll
    for (int dy = 0; dy < 32; dy += 8) {
        int n = n0 + threadIdx.y + dy;
        int k = k0 + threadIdx.x;
        if (n < jb.R && k < jb.C)
            tile[threadIdx.y+dy][threadIdx.x] = jb.src[(size_t)n*jb.C + k];
    }
    __syncthreads();
    #pragma unroll
    for (int dy = 0; dy < 32; dy += 8) {
        int k = k0 + threadIdx.y + dy;
        int n = n0 + threadIdx.x;
        if (k < jb.C && n < jb.R)
            jb.dst[(size_t)k*jb.ldo + jb.coff + n] = tile[threadIdx.x][threadIdx.y+dy];
    }
}

// ---------------------------------------------------------------------------
// K1: embedding gather
// ---------------------------------------------------------------------------
__global__ void embed_kernel(const int* __restrict__ wids, const int* __restrict__ uids,
                             const float* __restrict__ wl, const float* __restrict__ tl,
                             float* __restrict__ words) {
    int bt = blockIdx.x;
    int t = threadIdx.x;           // 128 threads
    int wid = wids[bt];
    int uid = uids[bt];
    if (t < WD)       words[bt*D + t] = wl[wid*WD + t];
    else if (t < D)   words[bt*D + t] = tl[uid*UD + (t - WD)];
}

// ---------------------------------------------------------------------------
// K2: projection GEMM, transposed weights, CPT columns per thread,
//     software-pipelined WT loads (prefetch next k-group).
// ---------------------------------------------------------------------------
#define MT 16
template<int CPT>
__global__ __launch_bounds__(512)
void proj_t(const float* __restrict__ x, const float* __restrict__ WT,
            const float* __restrict__ bias, float* __restrict__ out,
            int Ncols, int K, int ldx, const int* __restrict__ gather_idx) {
    __shared__ float xs[250 * 17 + 16];   // xs[k*17 + r]
    int m0 = blockIdx.x * MT;
    for (int e = threadIdx.x; e < MT * K; e += blockDim.x) {
        int r = e / K, k = e - r * K;
        int m = m0 + r;
        int row = m;
        if (gather_idx) {
            int bb = m >> 7, np = m & 127;
            row = (bb << 7) + (np == 0 ? 0 : gather_idx[m]);
        }
        xs[k*17 + r] = x[(size_t)row*ldx + k];
    }
    __syncthreads();
    int n0 = threadIdx.x;
    int lane = threadIdx.x & 63;
    int bd = blockDim.x;
    float acc[CPT][MT];
    int ncl[CPT];
    #pragma unroll
    for (int j = 0; j < CPT; j++) {
        int n = n0 + j*bd;
        ncl[j] = (n < Ncols) ? n : (Ncols - 1);
        #pragma unroll
        for (int r = 0; r < MT; r++) acc[j][r] = 0.0f;
    }
    float wkc[4][CPT];
    #pragma unroll
    for (int q = 0; q < 4; q++)
        #pragma unroll
        for (int j = 0; j < CPT; j++)
            wkc[q][j] = WT[(size_t)q*Ncols + ncl[j]];     // K >= 4 always
    int k0 = 0;
    for (; k0 + 8 <= K; k0 += 4) {
        float xv = xs[(k0 + (lane >> 4))*17 + (lane & 15)];
        float wkn[4][CPT];
        #pragma unroll
        for (int q = 0; q < 4; q++)
            #pragma unroll
            for (int j = 0; j < CPT; j++)
                wkn[q][j] = WT[(size_t)(k0 + 4 + q)*Ncols + ncl[j]];
        #pragma unroll
        for (int q = 0; q < 4; q++) {
            #pragma unroll
            for (int r = 0; r < 16; r++) {
                float hv = bcast_lane(xv, q*16 + r);
                #pragma unroll
                for (int j = 0; j < CPT; j++)
                    acc[j][r] = fmaf(wkc[q][j], hv, acc[j][r]);
            }
        }
        #pragma unroll
        for (int q = 0; q < 4; q++)
            #pragma unroll
            for (int j = 0; j < CPT; j++)
                wkc[q][j] = wkn[q][j];
    }
    { // last full group
        float xv = xs[(k0 + (lane >> 4))*17 + (lane & 15)];
        #pragma unroll
        for (int q = 0; q < 4; q++) {
            #pragma unroll
            for (int r = 0; r < 16; r++) {
                float hv = bcast_lane(xv, q*16 + r);
                #pragma unroll
                for (int j = 0; j < CPT; j++)
                    acc[j][r] = fmaf(wkc[q][j], hv, acc[j][r]);
            }
        }
        k0 += 4;
    }
    for (; k0 < K; k0++) {                 // tail (K=125 -> 1, K=250 -> 2)
        float xv = xs[k0*17 + (lane & 15)];
        float wk[CPT];
        #pragma unroll
        for (int j = 0; j < CPT; j++) wk[j] = WT[(size_t)k0*Ncols + ncl[j]];
        #pragma unroll
        for (int r = 0; r < 16; r++) {
            float hv = bcast_lane(xv, r);
            #pragma unroll
            for (int j = 0; j < CPT; j++)
                acc[j][r] = fmaf(wk[j], hv, acc[j][r]);
        }
    }
    #pragma unroll
    for (int j = 0; j < CPT; j++) {
        int n = n0 + j*bd;
        if (n < Ncols) {
            float bb = bias[n];
            #pragma unroll
            for (int r = 0; r < MT; r++) out[(size_t)(m0 + r)*Ncols + n] = acc[j][r] + bb;
        }
    }
}

// ---------------------------------------------------------------------------
// K3: LSTM scan v11. One block per (b,dir), 1024 threads, k-split halves.
//     khalf-0 weights (64x500 fp32 = 128 KB) are RESIDENT IN LDS (stride-66
//     rows => b64 reads at size-minimum bank utilization); khalf-1 weights
//     stream from L2 each step (separate memory pipe, overlaps LDS pipe).
//     Rationale: rounds 2-10 proved per-thread register residency is
//     unobtainable; LDS is the only on-CU storage that fits half the matrix.
// ---------------------------------------------------------------------------
#define WSTRIDE 66
#define SM_HOFF (500*WSTRIDE)            // 33000
#define SM_POFF (SM_HOFF + 128)          // 33128
#define SM_FLOATS (SM_POFF + 1024)       // 34152 floats = 136,608 B

__global__ __launch_bounds__(1024)
void lstm_scan(const float* __restrict__ xgc,
               const float* __restrict__ WhG,   // original [500][125] gate-major
               const float* __restrict__ WhT,   // [128][500] k-major, rows 125..127 zero
               float* __restrict__ out, int dir) {
    int b = blockIdx.x;
    int off = dir ? D : 0;
    int t = threadIdx.x;
    int g = t & 511;
    int half = t >> 9;
    int lane = t & 63;

    extern __shared__ float smem[];
    float* wlds = smem;            // [500][WSTRIDE]
    float* hbuf = smem + SM_HOFF;  // [128]
    float* pbuf = smem + SM_POFF;  // [1024]

    // stage khalf-0 weights: wlds[g2][i] = WhG[g2*125 + i], i in [0,64)
    for (int e = t; e < 500*64; e += 1024) {
        int g2 = e >> 6, i = e & 63;
        wlds[g2*WSTRIDE + i] = WhG[g2*125 + i];
    }
    if (t < 128) hbuf[t] = 0.0f;   // h[125..127] stay 0 forever (pad-safe)
    __syncthreads();

    const float* xb = xgc + (size_t)b * N * 1000 + dir * 500;
    bool xa = (half == 0) && (g < G4);
    float x_next = xa ? xb[(size_t)(dir ? (N-1) : 0) * 1000 + g] : 0.0f;
    float c = 0.0f;

    const float2* wr = (const float2*)(wlds + g*WSTRIDE);   // g*264 % 8 == 0
    const float* ws = WhT + 64*500 + g;                      // stream base (khalf1)

    for (int ti = 0; ti < N; ti++) {
        int tt = dir ? (N-1-ti) : ti;
        float x_cur = x_next;
        float xn = 0.0f;
        if (xa && ti + 1 < N)
            xn = xb[(size_t)(dir ? (tt-1) : (tt+1)) * 1000 + g];

        float a0 = x_cur, a1 = 0.0f, a2 = 0.0f, a3 = 0.0f;
        if (half == 0) {
            float hseg = hbuf[lane];                 // h[0..63]
            #pragma unroll
            for (int j = 0; j < 16; j++) {           // 32 float2 = 64 weights
                float2 w0 = wr[2*j], w1 = wr[2*j+1];
                a0 = fmaf(w0.x, bcast_lane(hseg, 4*j    ), a0);
                a1 = fmaf(w0.y, bcast_lane(hseg, 4*j + 1), a1);
                a2 = fmaf(w1.x, bcast_lane(hseg, 4*j + 2), a2);
                a3 = fmaf(w1.y, bcast_lane(hseg, 4*j + 3), a3);
            }
        } else {
            float hseg = hbuf[64 + lane];            // h[64..127]; 125..127 == 0
            float cw[8];
            #pragma unroll
            for (int q = 0; q < 8; q++) cw[q] = ws[(size_t)q*500];
            #pragma unroll
            for (int ch = 0; ch < 8; ch++) {
                float nw[8];
                if (ch < 7) {
                    #pragma unroll
                    for (int q = 0; q < 8; q++) nw[q] = ws[(size_t)((ch+1)*8 + q)*500];
                }
                #pragma unroll
                for (int q = 0; q < 8; q++) {
                    int i = ch*8 + q;                // k = 64 + i; i in [61,64) has w==0
                    float hv = bcast_lane(hseg, i);
                    if ((i & 3) == 0)      a0 = fmaf(cw[q], hv, a0);
                    else if ((i & 3) == 1) a1 = fmaf(cw[q], hv, a1);
                    else if ((i & 3) == 2) a2 = fmaf(cw[q], hv, a2);
                    else                   a3 = fmaf(cw[q], hv, a3);
                }
                if (ch < 7) {
                    #pragma unroll
                    for (int q = 0; q < 8; q++) cw[q] = nw[q];
                }
            }
        }
        x_next = xn;
        pbuf[t] = (a0 + a1) + (a2 + a3);
        __syncthreads();
        if (t < D) {
            float iv = pbuf[t]       + pbuf[512 + t];
            float fv = pbuf[D+t]     + pbuf[512 + D+t];
            float gv = pbuf[2*D+t]   + pbuf[512 + 2*D+t];
            float ov = pbuf[3*D+t]   + pbuf[512 + 3*D+t];
            float si = fast_sigmoid(iv);
            float sf = fast_sigmoid(fv);
            float so = fast_sigmoid(ov);
            c = sf * c + si * fast_tanh(gv);
            float h = so * fast_tanh(c);
            hbuf[t] = h;
            out[(size_t)(b*N + tt)*H2 + off + t] = h;
        }
        __syncthreads();
    }
}

// ---------------------------------------------------------------------------
// K4: arc scores + margin + argmax. Block per (b, 4-i tile); 128 threads (j).
// ---------------------------------------------------------------------------
#define ITILE 4
__global__ __launch_bounds__(128)
void arc_kernel(const float* __restrict__ s3,
                const float* __restrict__ esW, const float* __restrict__ esb,
                const int* __restrict__ ta,
                float* __restrict__ arc_out, float* __restrict__ tree_out) {
    int blk = blockIdx.x;             // b*32 + it
    int b = blk >> 5, it = blk & 31;
    int j = threadIdx.x;              // 128 threads

    __shared__ float wms[128 * 101];
    __shared__ float whs[ITILE][HID];
    __shared__ float es[HID];
    __shared__ float sv[128];
    __shared__ int   si[128];

    for (int e = j; e < 128 * HID; e += 128) {
        int r = e / HID, h = e - r * HID;
        wms[r*101 + h] = s3[(size_t)(b*N + r)*300 + 100 + h];
    }
    for (int e = j; e < ITILE * HID; e += 128) {
        int ii = e / HID, h = e - ii * HID;
        whs[ii][h] = s3[(size_t)(b*N + it*ITILE + ii)*300 + h];
    }
    if (j < HID) es[j] = esW[j];
    __syncthreads();

    float eb = esb[0];
    const float* wmr = &wms[j * 101];
    for (int ii = 0; ii < ITILE; ii++) {
        int i = it * ITILE + ii;
        int bi = b * N + i;
        float acc = 0.0f;
        for (int h = 0; h < HID; h++)
            acc = fmaf(es[h], fast_tanh(whs[ii][h] + wmr[h]), acc);
        int tai = (i == 0) ? 0 : ta[bi];
        float score = acc + eb + 1.0f - ((j == tai) ? 1.0f : 0.0f);
        arc_out[(size_t)bi*N + j] = score;
        sv[j] = score; si[j] = j;
        __syncthreads();
        for (int s = 64; s; s >>= 1) {
            if (j < s) {
                float ov = sv[j+s]; int oi = si[j+s];
                if (ov > sv[j] || (ov == sv[j] && oi < si[j])) { sv[j] = ov; si[j] = oi; }
            }
            __syncthreads();
        }
        if (j == 0) tree_out[bi] = (float)si[0];
        __syncthreads();
    }
}

// ---------------------------------------------------------------------------
// K5: rel scores + argmax. One block (64 threads) per bt.
// ---------------------------------------------------------------------------
__global__ void rel_kernel(const float* __restrict__ s3, const float* __restrict__ rh,
                           const float* __restrict__ lsW, const float* __restrict__ lsb,
                           float* __restrict__ rel_out, float* __restrict__ pred_out) {
    int bt = blockIdx.x;
    int t = threadIdx.x;          // 64 threads

    __shared__ float tv[HID];
    __shared__ float sv[64];
    __shared__ int   si[64];

    for (int h = t; h < HID; h += 64)
        tv[h] = fast_tanh(s3[(size_t)bt*300 + 200 + h] + rh[(size_t)bt*HID + h]);
    __syncthreads();

    float score = -1e30f;
    if (t < L) {
        float acc = 0.0f;
        const float* wrow = lsW + t*HID;
        for (int h = 0; h < HID; h++) acc = fmaf(wrow[h], tv[h], acc);
        score = acc + lsb[t];
        rel_out[(size_t)bt*L + t] = score;
    }
    sv[t] = score;
    si[t] = t;
    __syncthreads();
    for (int s = 32; s; s >>= 1) {
        if (t < s) {
            float ov = sv[t + s]; int oi = si[t + s];
            if (ov > sv[t] || (ov == sv[t] && oi < si[t])) { sv[t] = ov; si[t] = oi; }
        }
        __syncthreads();
    }
    if (t == 0) pred_out[bt] = (float)si[0];
}

// ---------------------------------------------------------------------------
extern "C" void kernel_launch(void* const* d_in, const int* in_sizes, int n_in,
                              void* d_out, int out_size, void* d_ws, size_t ws_size,
                              hipStream_t stream) {
    const int*   word_ids    = (const int*)  d_in[0];
    const int*   upos_ids    = (const int*)  d_in[1];
    const int*   target_arcs = (const int*)  d_in[2];
    const float* wlookup     = (const float*)d_in[3];
    const float* tlookup     = (const float*)d_in[4];
    const float* l0f_Wih = (const float*)d_in[5];
    const float* l0f_Whh = (const float*)d_in[6];
    const float* l0f_b   = (const float*)d_in[7];
    const float* l0b_Wih = (const float*)d_in[8];
    const float* l0b_Whh = (const float*)d_in[9];
    const float* l0b_b   = (const float*)d_in[10];
    const float* l1f_Wih = (const float*)d_in[11];
    const float* l1f_Whh = (const float*)d_in[12];
    const float* l1f_b   = (const float*)d_in[13];
    const float* l1b_Wih = (const float*)d_in[14];
    const float* l1b_Whh = (const float*)d_in[15];
    const float* l1b_b   = (const float*)d_in[16];
    const float* eh_W = (const float*)d_in[17];
    const float* eh_b = (const float*)d_in[18];
    const float* em_W = (const float*)d_in[19];
    const float* em_b = (const float*)d_in[20];
    const float* es_W = (const float*)d_in[21];
    const float* es_b = (const float*)d_in[22];
    const float* lh_W = (const float*)d_in[23];
    const float* lh_b = (const float*)d_in[24];
    const float* lm_W = (const float*)d_in[25];
    const float* lm_b = (const float*)d_in[26];
    const float* ls_W = (const float*)d_in[27];
    const float* ls_b = (const float*)d_in[28];

    float* out = (float*)d_out;
    float* trees_out = out;                         // 4096
    float* preds_out = out + BT;                    // 4096
    float* arc_out   = out + 2*BT;                  // 524288
    float* rel_out   = out + 2*BT + BT*N;           // 204800

    float* ws = (float*)d_ws;
    float* A       = ws;                    // 4,096,000: xg fused [m][1000]; later s3 [m][300]
    float* words   = ws + 4096000;          //   512,000
    float* C       = ws + 4608000;          // 1,024,000: h0, then ex
    float* WT_l0   = ws + 5632000;          //   125,000  [125][1000]
    float* WT_l1   = ws + 5757000;          //   250,000  [250][1000]
    float* WT_s3   = ws + 6007000;          //    75,000  [250][300]
    float* WT_lh   = ws + 6082000;          //    25,000  [250][100]
    float* WhT_l0f = ws + 6107000;          //    64,016  [128][500]+16 (pad rows zeroed)
    float* WhT_l0b = ws + 6171016;          //    64,016
    float* WhT_l1f = ws + 6235032;          //    64,016
    float* WhT_l1b = ws + 6299048;          //    64,016
    float* b_l0    = ws + 6363064;          //     1,000
    float* b_l1    = ws + 6364064;          //     1,000
    float* b_s3    = ws + 6365064;          //     1,000 (300 used)
    float* rel_head = ws + 6366064;         //   409,600  [m][100]
    // total 6,775,664 floats = 27.1 MB

    // 0. fused biases + pad-row zeroing + fused tiled transpose (12 matrices)
    bias_setup<<<9, 256, 0, stream>>>(l0f_b, l0b_b, l1f_b, l1b_b, eh_b, em_b, lm_b,
                                      b_l0, b_l1, b_s3);
    pad_zero<<<24, 256, 0, stream>>>(WhT_l0f, WhT_l0b, WhT_l1f, WhT_l1b);
    {
        TArgs ta{};
        auto tiles = [](int R, int C_) { return ((C_+31)/32) * ((R+31)/32); };
        struct { const float* s; float* d; int R, C, ldo, coff; } js[12] = {
            { l0f_Wih, WT_l0, 500, 125, 1000, 0 },
            { l0b_Wih, WT_l0, 500, 125, 1000, 500 },
            { l1f_Wih, WT_l1, 500, 250, 1000, 0 },
            { l1b_Wih, WT_l1, 500, 250, 1000, 500 },
            { eh_W, WT_s3, 100, 250, 300, 0 },
            { em_W, WT_s3, 100, 250, 300, 100 },
            { lm_W, WT_s3, 100, 250, 300, 200 },
            { lh_W, WT_lh, 100, 250, 100, 0 },
            { l0f_Whh, WhT_l0f, 500, 125, 500, 0 },
            { l0b_Whh, WhT_l0b, 500, 125, 500, 0 },
            { l1f_Whh, WhT_l1f, 500, 125, 500, 0 },
            { l1b_Whh, WhT_l1b, 500, 125, 500, 0 },
        };
        int t0 = 0;
        for (int i = 0; i < 12; i++) {
            ta.j[i].src = js[i].s;  ta.j[i].dst = js[i].d;
            ta.j[i].R = js[i].R;    ta.j[i].C = js[i].C;
            ta.j[i].ldo = js[i].ldo; ta.j[i].coff = js[i].coff;
            ta.j[i].tile0 = t0;
            ta.j[i].tiles_x = (js[i].C + 31) / 32;
            t0 += tiles(js[i].R, js[i].C);
        }
        transpose_fused<<<t0, dim3(32, 8), 0, stream>>>(ta);
    }

    // 1. embeddings
    embed_kernel<<<BT, 128, 0, stream>>>(word_ids, upos_ids, wlookup, tlookup, words);

    // 2. layer-0 input projections, fused fwd+bwd (K=125, N=1000)
    proj_t<2><<<BT/MT, 512, 0, stream>>>(words, WT_l0, b_l0, A, 1000, D, D, nullptr);

    // 3. layer-0 scan -> h0 (C): fwd + bwd as separate 32-block launches
    size_t smem_bytes = (size_t)SM_FLOATS * 4;
    lstm_scan<<<B, 1024, smem_bytes, stream>>>(A, l0f_Whh, WhT_l0f, C, 0);
    lstm_scan<<<B, 1024, smem_bytes, stream>>>(A, l0b_Whh, WhT_l0b, C, 1);

    // 4. layer-1 input projections (K=250, N=1000)
    proj_t<2><<<BT/MT, 512, 0, stream>>>(C, WT_l1, b_l1, A, 1000, H2, H2, nullptr);

    // 5. layer-1 scan -> ex (C, overwrites h0)
    lstm_scan<<<B, 1024, smem_bytes, stream>>>(A, l1f_Whh, WhT_l1f, C, 0);
    lstm_scan<<<B, 1024, smem_bytes, stream>>>(A, l1b_Whh, WhT_l1b, C, 1);

    // 6. scorer projections: eh+em+lm fused (N=300) into A; lh gathered (N=100)
    proj_t<2><<<BT/MT, 192, 0, stream>>>(C, WT_s3, b_s3, A, 300, H2, H2, nullptr);
    proj_t<1><<<BT/MT, 128, 0, stream>>>(C, WT_lh, lh_b, rel_head, 100, H2, H2, target_arcs);

    // 7. arc scores + margin + argmax
    arc_kernel<<<BT/ITILE, 128, 0, stream>>>(A, es_W, es_b, target_arcs,
                                             arc_out, trees_out);

    // 8. rel scores + argmax
    rel_kernel<<<BT, 64, 0, stream>>>(A, rel_head, ls_W, ls_b, rel_out, preds_out);
}

// Round 12
// 593.282 us; speedup vs baseline: 6.5887x; 6.5887x over previous
//
#include <hip/hip_runtime.h>
#include <hip/hip_bf16.h>
#include <math.h>

// Problem constants
#define B 32
#define N 128
#define BT (B*N)          // 4096
#define WD 100
#define UD 25
#define D 125             // LSTM hidden per direction
#define G4 (4*D)          // 500 gates
#define H2 (2*D)          // 250
#define HID 100
#define L 50

// Fast, overflow-safe activations on v_exp_f32
__device__ __forceinline__ float fast_tanh(float x) {
    float e = __expf(2.0f * x);
    return 1.0f - 2.0f / (e + 1.0f);
}
__device__ __forceinline__ float fast_sigmoid(float x) {
    return 1.0f / (1.0f + __expf(-x));
}
__device__ __forceinline__ float bcast_lane(float v, int k) {
    return __builtin_bit_cast(float, __builtin_amdgcn_readlane(__builtin_bit_cast(int, v), k));
}

// 64-way macro repetition
#define REP64(X) \
 X(0) X(1) X(2) X(3) X(4) X(5) X(6) X(7) X(8) X(9) \
 X(10) X(11) X(12) X(13) X(14) X(15) X(16) X(17) X(18) X(19) \
 X(20) X(21) X(22) X(23) X(24) X(25) X(26) X(27) X(28) X(29) \
 X(30) X(31) X(32) X(33) X(34) X(35) X(36) X(37) X(38) X(39) \
 X(40) X(41) X(42) X(43) X(44) X(45) X(46) X(47) X(48) X(49) \
 X(50) X(51) X(52) X(53) X(54) X(55) X(56) X(57) X(58) X(59) \
 X(60) X(61) X(62) X(63)

// ---------------------------------------------------------------------------
// K_setup: ONE launch for {12 weight transposes, embedding gather, fused
// biases, WhT pad-row zeroing}. Grid partition: [0,TR) transpose tiles,
// [TR,TR+2048) embed (2 bt/block), then 9 bias blocks, then 24 pad blocks.
// ---------------------------------------------------------------------------
struct TJob { const float* src; float* dst; int R, C, ldo, coff, tile0, tiles_x; };
struct TArgs { TJob j[12]; };

__global__ __launch_bounds__(256)
void setup_fused(TArgs a, int n_tr,
                 const int* __restrict__ wids, const int* __restrict__ uids,
                 const float* __restrict__ wl, const float* __restrict__ tl,
                 float* __restrict__ words,
                 const float* __restrict__ l0f_b, const float* __restrict__ l0b_b,
                 const float* __restrict__ l1f_b, const float* __restrict__ l1b_b,
                 const float* __restrict__ eh_b, const float* __restrict__ em_b,
                 const float* __restrict__ lm_b,
                 float* __restrict__ b_l0, float* __restrict__ b_l1,
                 float* __restrict__ b_s3,
                 float* __restrict__ p0, float* __restrict__ p1,
                 float* __restrict__ p2, float* __restrict__ p3) {
    __shared__ float tile[32][33];
    int bid = blockIdx.x;
    int tid = threadIdx.x;
    if (bid < n_tr) {                    // ---- transpose tiles ----
        int ji = 0;
        #pragma unroll
        for (int i = 1; i < 12; i++) if (bid >= a.j[i].tile0) ji = i;
        TJob jb = a.j[ji];
        int t = bid - jb.tile0;
        int tx = t % jb.tiles_x, ty = t / jb.tiles_x;
        int txx = tid & 31, tyy = tid >> 5;      // 32 x 8
        int k0 = tx*32, n0 = ty*32;
        #pragma unroll
        for (int dy = 0; dy < 32; dy += 8) {
            int n = n0 + tyy + dy, k = k0 + txx;
            if (n < jb.R && k < jb.C)
                tile[tyy+dy][txx] = jb.src[(size_t)n*jb.C + k];
        }
        __syncthreads();
        #pragma unroll
        for (int dy = 0; dy < 32; dy += 8) {
            int k = k0 + tyy + dy, n = n0 + txx;
            if (k < jb.C && n < jb.R)
                jb.dst[(size_t)k*jb.ldo + jb.coff + n] = tile[txx][tyy+dy];
        }
        return;
    }
    bid -= n_tr;
    if (bid < 2048) {                    // ---- embed: 2 bt per block ----
        int bt = bid*2 + (tid >> 7);
        int t = tid & 127;
        int wid = wids[bt], uid = uids[bt];
        if (t < WD)       words[bt*D + t] = wl[(size_t)wid*WD + t];
        else if (t < D)   words[bt*D + t] = tl[(size_t)uid*UD + (t - WD)];
        return;
    }
    bid -= 2048;
    if (bid < 9) {                       // ---- fused biases ----
        int t = bid*256 + tid;
        if (t < 500)        b_l0[t] = l0f_b[t];
        else if (t < 1000)  b_l0[t] = l0b_b[t-500];
        else if (t < 1500)  b_l1[t-1000] = l1f_b[t-1000];
        else if (t < 2000)  b_l1[t-1000] = l1b_b[t-1500];
        else if (t < 2100)  b_s3[t-2000] = eh_b[t-2000];
        else if (t < 2200)  b_s3[t-2000] = em_b[t-2100];
        else if (t < 2300)  b_s3[t-2000] = lm_b[t-2200];
        return;
    }
    bid -= 9;                            // ---- pad-row zeroing (24 blocks) ----
    int e = bid*256 + tid;               // < 6144; need 4*1516 = 6064
    if (e < 6064) {
        int m = e / 1516, o = e % 1516;
        float* p = (m == 0) ? p0 : (m == 1) ? p1 : (m == 2) ? p2 : p3;
        p[125*500 + o] = 0.0f;
    }
}

// ---------------------------------------------------------------------------
// K2: projection GEMM, transposed weights, CPT columns per thread,
//     software-pipelined WT loads (prefetch next k-group).
// ---------------------------------------------------------------------------
#define MT 16
template<int CPT, int BD>
__device__ __forceinline__
void proj_body(const float* __restrict__ x, const float* __restrict__ WT,
               const float* __restrict__ bias, float* __restrict__ out,
               int Ncols, int K, int ldx, const int* __restrict__ gather_idx,
               int blk, float* xs) {
    int m0 = blk * MT;
    for (int e = threadIdx.x; e < MT * K; e += BD) {
        int r = e / K, k = e - r * K;
        int m = m0 + r;
        int row = m;
        if (gather_idx) {
            int bb = m >> 7, np = m & 127;
            row = (bb << 7) + (np == 0 ? 0 : gather_idx[m]);
        }
        xs[k*17 + r] = x[(size_t)row*ldx + k];
    }
    __syncthreads();
    int n0 = threadIdx.x;
    int lane = threadIdx.x & 63;
    float acc[CPT][MT];
    int ncl[CPT];
    #pragma unroll
    for (int j = 0; j < CPT; j++) {
        int n = n0 + j*BD;
        ncl[j] = (n < Ncols) ? n : (Ncols - 1);
        #pragma unroll
        for (int r = 0; r < MT; r++) acc[j][r] = 0.0f;
    }
    float wkc[4][CPT];
    #pragma unroll
    for (int q = 0; q < 4; q++)
        #pragma unroll
        for (int j = 0; j < CPT; j++)
            wkc[q][j] = WT[(size_t)q*Ncols + ncl[j]];
    int k0 = 0;
    for (; k0 + 8 <= K; k0 += 4) {
        float xv = xs[(k0 + (lane >> 4))*17 + (lane & 15)];
        float wkn[4][CPT];
        #pragma unroll
        for (int q = 0; q < 4; q++)
            #pragma unroll
            for (int j = 0; j < CPT; j++)
                wkn[q][j] = WT[(size_t)(k0 + 4 + q)*Ncols + ncl[j]];
        #pragma unroll
        for (int q = 0; q < 4; q++) {
            #pragma unroll
            for (int r = 0; r < 16; r++) {
                float hv = bcast_lane(xv, q*16 + r);
                #pragma unroll
                for (int j = 0; j < CPT; j++)
                    acc[j][r] = fmaf(wkc[q][j], hv, acc[j][r]);
            }
        }
        #pragma unroll
        for (int q = 0; q < 4; q++)
            #pragma unroll
            for (int j = 0; j < CPT; j++)
                wkc[q][j] = wkn[q][j];
    }
    { // last full group
        float xv = xs[(k0 + (lane >> 4))*17 + (lane & 15)];
        #pragma unroll
        for (int q = 0; q < 4; q++) {
            #pragma unroll
            for (int r = 0; r < 16; r++) {
                float hv = bcast_lane(xv, q*16 + r);
                #pragma unroll
                for (int j = 0; j < CPT; j++)
                    acc[j][r] = fmaf(wkc[q][j], hv, acc[j][r]);
            }
        }
        k0 += 4;
    }
    for (; k0 < K; k0++) {
        float xv = xs[k0*17 + (lane & 15)];
        float wk[CPT];
        #pragma unroll
        for (int j = 0; j < CPT; j++) wk[j] = WT[(size_t)k0*Ncols + ncl[j]];
        #pragma unroll
        for (int r = 0; r < 16; r++) {
            float hv = bcast_lane(xv, r);
            #pragma unroll
            for (int j = 0; j < CPT; j++)
                acc[j][r] = fmaf(wk[j], hv, acc[j][r]);
        }
    }
    #pragma unroll
    for (int j = 0; j < CPT; j++) {
        int n = n0 + j*BD;
        if (n < Ncols) {
            float bb = bias[n];
            #pragma unroll
            for (int r = 0; r < MT; r++) out[(size_t)(m0 + r)*Ncols + n] = acc[j][r] + bb;
        }
    }
}

__global__ __launch_bounds__(512)
void proj_t(const float* __restrict__ x, const float* __restrict__ WT,
            const float* __restrict__ bias, float* __restrict__ out,
            int Ncols, int K, int ldx) {
    __shared__ float xs[250 * 17 + 16];
    proj_body<2, 512>(x, WT, bias, out, Ncols, K, ldx, nullptr, blockIdx.x, xs);
}

// fused scorer projections: blocks [0,256) -> s3 (Ncols=300), [256,512) -> lh
__global__ __launch_bounds__(256)
void proj_s3lh(const float* __restrict__ x,
               const float* __restrict__ WTa, const float* __restrict__ ba,
               float* __restrict__ outa,
               const float* __restrict__ WTb, const float* __restrict__ bb,
               float* __restrict__ outb, const int* __restrict__ gather_idx) {
    __shared__ float xs[250 * 17 + 16];
    int job = blockIdx.x >> 8;
    int blk = blockIdx.x & 255;
    if (job == 0)
        proj_body<2, 256>(x, WTa, ba, outa, 300, H2, H2, nullptr, blk, xs);
    else
        proj_body<2, 256>(x, WTb, bb, outb, 100, H2, H2, gather_idx, blk, xs);
}

// ---------------------------------------------------------------------------
// K3: LSTM scan — round-8 version verbatim (best measured: 140 us).
// ---------------------------------------------------------------------------
__global__ __launch_bounds__(1024, 4)
void lstm_scan(const float* __restrict__ xgc,
               const float* __restrict__ WhTf, const float* __restrict__ WhTb,
               float* __restrict__ out) {
    int dir = blockIdx.x & 1;
    int b = blockIdx.x >> 1;
    const float* WhT = dir ? WhTb : WhTf;   // [128][500], zero-padded rows 125..127
    int off = dir ? D : 0;
    int t = threadIdx.x;
    int g = t & 511;
    int half = t >> 9;
    int kbase = half << 6;                  // 0 or 64

    __shared__ __align__(16) float hbuf[128];
    __shared__ float pbuf[1024];

    unsigned voff0 = ((unsigned)kbase * 500u + (unsigned)g) * 4u;
#define DECLW(i) float w##i; \
    asm volatile("global_load_dword %0, %1, %2" \
                 : "=v"(w##i) : "v"(voff0 + (unsigned)(i)*2000u), "s"(WhT));
    REP64(DECLW)
#undef DECLW
    asm volatile("s_waitcnt vmcnt(0)" ::: "memory");

    float c = 0.0f;
    if (t < 128) hbuf[t] = 0.0f;
    __syncthreads();

    const float* xb = xgc + (size_t)b * N * 1000 + dir * 500;
    bool xa = (half == 0) && (g < G4);
    float x_next = xa ? xb[(size_t)(dir ? (N-1) : 0) * 1000 + g] : 0.0f;

    const float4* h4q = ((const float4*)hbuf) + (kbase >> 2);

#define FMA4(q, i0, i1, i2, i3) { float4 hv = h4q[q]; \
    a4[0] = fmaf(w##i0, hv.x, a4[0]); \
    a4[1] = fmaf(w##i1, hv.y, a4[1]); \
    a4[2] = fmaf(w##i2, hv.z, a4[2]); \
    a4[3] = fmaf(w##i3, hv.w, a4[3]); }

    for (int ti = 0; ti < N; ti++) {
        int tt = dir ? (N-1-ti) : ti;
        float x_cur = x_next;
        float xn = 0.0f;
        if (xa && ti + 1 < N)
            xn = xb[(size_t)(dir ? (tt-1) : (tt+1)) * 1000 + g];
        float a4[4];
        a4[0] = x_cur; a4[1] = 0.0f; a4[2] = 0.0f; a4[3] = 0.0f;
        FMA4(0,  0,  1,  2,  3)  FMA4(1,  4,  5,  6,  7)
        FMA4(2,  8,  9, 10, 11)  FMA4(3, 12, 13, 14, 15)
        FMA4(4, 16, 17, 18, 19)  FMA4(5, 20, 21, 22, 23)
        FMA4(6, 24, 25, 26, 27)  FMA4(7, 28, 29, 30, 31)
        FMA4(8, 32, 33, 34, 35)  FMA4(9, 36, 37, 38, 39)
        FMA4(10, 40, 41, 42, 43) FMA4(11, 44, 45, 46, 47)
        FMA4(12, 48, 49, 50, 51) FMA4(13, 52, 53, 54, 55)
        FMA4(14, 56, 57, 58, 59) FMA4(15, 60, 61, 62, 63)
        x_next = xn;
        pbuf[t] = (a4[0] + a4[1]) + (a4[2] + a4[3]);
        __syncthreads();
        if (t < D) {
            float iv = pbuf[t]       + pbuf[512 + t];
            float fv = pbuf[D+t]     + pbuf[512 + D+t];
            float gv = pbuf[2*D+t]   + pbuf[512 + 2*D+t];
            float ov = pbuf[3*D+t]   + pbuf[512 + 3*D+t];
            float si = fast_sigmoid(iv);
            float sf = fast_sigmoid(fv);
            float so = fast_sigmoid(ov);
            c = sf * c + si * fast_tanh(gv);
            float h = so * fast_tanh(c);
            hbuf[t] = h;
            out[(size_t)(b*N + tt)*H2 + off + t] = h;
        }
        __syncthreads();
    }
#undef FMA4
}

// ---------------------------------------------------------------------------
// K4: fused arc + rel. Blocks [0,1024): arc (b, 4-i tile); [1024,5120): rel.
// ---------------------------------------------------------------------------
#define ITILE 4
__global__ __launch_bounds__(128)
void arc_rel(const float* __restrict__ s3,
             const float* __restrict__ esW, const float* __restrict__ esb,
             const int* __restrict__ ta, const float* __restrict__ rh,
             const float* __restrict__ lsW, const float* __restrict__ lsb,
             float* __restrict__ arc_out, float* __restrict__ tree_out,
             float* __restrict__ rel_out, float* __restrict__ pred_out) {
    __shared__ float wms[128 * 101];
    __shared__ float whs[ITILE][HID];
    __shared__ float es[HID];
    __shared__ float sv[128];
    __shared__ int   si[128];
    int j = threadIdx.x;

    if (blockIdx.x < 1024) {             // ---------- arc ----------
        int blk = blockIdx.x;
        int b = blk >> 5, it = blk & 31;
        for (int e = j; e < 128 * HID; e += 128) {
            int r = e / HID, h = e - r * HID;
            wms[r*101 + h] = s3[(size_t)(b*N + r)*300 + 100 + h];
        }
        for (int e = j; e < ITILE * HID; e += 128) {
            int ii = e / HID, h = e - ii * HID;
            whs[ii][h] = s3[(size_t)(b*N + it*ITILE + ii)*300 + h];
        }
        if (j < HID) es[j] = esW[j];
        __syncthreads();
        float eb = esb[0];
        const float* wmr = &wms[j * 101];
        for (int ii = 0; ii < ITILE; ii++) {
            int i = it * ITILE + ii;
            int bi = b * N + i;
            float acc = 0.0f;
            for (int h = 0; h < HID; h++)
                acc = fmaf(es[h], fast_tanh(whs[ii][h] + wmr[h]), acc);
            int tai = (i == 0) ? 0 : ta[bi];
            float score = acc + eb + 1.0f - ((j == tai) ? 1.0f : 0.0f);
            arc_out[(size_t)bi*N + j] = score;
            sv[j] = score; si[j] = j;
            __syncthreads();
            for (int s = 64; s; s >>= 1) {
                if (j < s) {
                    float ov = sv[j+s]; int oi = si[j+s];
                    if (ov > sv[j] || (ov == sv[j] && oi < si[j])) { sv[j] = ov; si[j] = oi; }
                }
                __syncthreads();
            }
            if (j == 0) tree_out[bi] = (float)si[0];
            __syncthreads();
        }
    } else {                             // ---------- rel ----------
        int bt = blockIdx.x - 1024;
        float* tv = es;                  // reuse 100-float buffer
        if (j < HID)
            tv[j] = fast_tanh(s3[(size_t)bt*300 + 200 + j] + rh[(size_t)bt*HID + j]);
        __syncthreads();
        float score = -1e30f;
        if (j < L) {
            float acc = 0.0f;
            const float* wrow = lsW + j*HID;
            for (int h = 0; h < HID; h++) acc = fmaf(wrow[h], tv[h], acc);
            score = acc + lsb[j];
            rel_out[(size_t)bt*L + j] = score;
        }
        sv[j] = score; si[j] = j;
        __syncthreads();
        for (int s = 64; s; s >>= 1) {
            if (j < s) {
                float ov = sv[j+s]; int oi = si[j+s];
                if (ov > sv[j] || (ov == sv[j] && oi < si[j])) { sv[j] = ov; si[j] = oi; }
            }
            __syncthreads();
        }
        if (j == 0) pred_out[bt] = (float)si[0];
    }
}

// ---------------------------------------------------------------------------
extern "C" void kernel_launch(void* const* d_in, const int* in_sizes, int n_in,
                              void* d_out, int out_size, void* d_ws, size_t ws_size,
                              hipStream_t stream) {
    const int*   word_ids    = (const int*)  d_in[0];
    const int*   upos_ids    = (const int*)  d_in[1];
    const int*   target_arcs = (const int*)  d_in[2];
    const float* wlookup     = (const float*)d_in[3];
    const float* tlookup     = (const float*)d_in[4];
    const float* l0f_Wih = (const float*)d_in[5];
    const float* l0f_Whh = (const float*)d_in[6];
    const float* l0f_b   = (const float*)d_in[7];
    const float* l0b_Wih = (const float*)d_in[8];
    const float* l0b_Whh = (const float*)d_in[9];
    const float* l0b_b   = (const float*)d_in[10];
    const float* l1f_Wih = (const float*)d_in[11];
    const float* l1f_Whh = (const float*)d_in[12];
    const float* l1f_b   = (const float*)d_in[13];
    const float* l1b_Wih = (const float*)d_in[14];
    const float* l1b_Whh = (const float*)d_in[15];
    const float* l1b_b   = (const float*)d_in[16];
    const float* eh_W = (const float*)d_in[17];
    const float* eh_b = (const float*)d_in[18];
    const float* em_W = (const float*)d_in[19];
    const float* em_b = (const float*)d_in[20];
    const float* es_W = (const float*)d_in[21];
    const float* es_b = (const float*)d_in[22];
    const float* lh_W = (const float*)d_in[23];
    const float* lh_b = (const float*)d_in[24];
    const float* lm_W = (const float*)d_in[25];
    const float* lm_b = (const float*)d_in[26];
    const float* ls_W = (const float*)d_in[27];
    const float* ls_b = (const float*)d_in[28];

    float* out = (float*)d_out;
    float* trees_out = out;                         // 4096
    float* preds_out = out + BT;                    // 4096
    float* arc_out   = out + 2*BT;                  // 524288
    float* rel_out   = out + 2*BT + BT*N;           // 204800

    float* ws = (float*)d_ws;
    float* A       = ws;                    // 4,096,000: xg fused [m][1000]; later s3 [m][300]
    float* words   = ws + 4096000;          //   512,000
    float* C       = ws + 4608000;          // 1,024,000: h0, then ex
    float* WT_l0   = ws + 5632000;          //   125,000  [125][1000]
    float* WT_l1   = ws + 5757000;          //   250,000  [250][1000]
    float* WT_s3   = ws + 6007000;          //    75,000  [250][300]
    float* WT_lh   = ws + 6082000;          //    25,000  [250][100]
    float* WhT_l0f = ws + 6107000;          //    64,016  [128][500]+16 (pad rows zeroed)
    float* WhT_l0b = ws + 6171016;          //    64,016
    float* WhT_l1f = ws + 6235032;          //    64,016
    float* WhT_l1b = ws + 6299048;          //    64,016
    float* b_l0    = ws + 6363064;          //     1,000
    float* b_l1    = ws + 6364064;          //     1,000
    float* b_s3    = ws + 6365064;          //     1,000 (300 used)
    float* rel_head = ws + 6366064;         //   409,600  [m][100]
    // total 6,775,664 floats = 27.1 MB

    // 0. single fused setup launch
    TArgs ta{};
    int n_tr = 0;
    {
        auto tiles = [](int R, int C_) { return ((C_+31)/32) * ((R+31)/32); };
        struct { const float* s; float* d; int R, C, ldo, coff; } js[12] = {
            { l0f_Wih, WT_l0, 500, 125, 1000, 0 },
            { l0b_Wih, WT_l0, 500, 125, 1000, 500 },
            { l1f_Wih, WT_l1, 500, 250, 1000, 0 },
            { l1b_Wih, WT_l1, 500, 250, 1000, 500 },
            { eh_W, WT_s3, 100, 250, 300, 0 },
            { em_W, WT_s3, 100, 250, 300, 100 },
            { lm_W, WT_s3, 100, 250, 300, 200 },
            { lh_W, WT_lh, 100, 250, 100, 0 },
            { l0f_Whh, WhT_l0f, 500, 125, 500, 0 },
            { l0b_Whh, WhT_l0b, 500, 125, 500, 0 },
            { l1f_Whh, WhT_l1f, 500, 125, 500, 0 },
            { l1b_Whh, WhT_l1b, 500, 125, 500, 0 },
        };
        for (int i = 0; i < 12; i++) {
            ta.j[i].src = js[i].s;  ta.j[i].dst = js[i].d;
            ta.j[i].R = js[i].R;    ta.j[i].C = js[i].C;
            ta.j[i].ldo = js[i].ldo; ta.j[i].coff = js[i].coff;
            ta.j[i].tile0 = n_tr;
            ta.j[i].tiles_x = (js[i].C + 31) / 32;
            n_tr += tiles(js[i].R, js[i].C);
        }
    }
    setup_fused<<<n_tr + 2048 + 9 + 24, 256, 0, stream>>>(
        ta, n_tr, word_ids, upos_ids, wlookup, tlookup, words,
        l0f_b, l0b_b, l1f_b, l1b_b, eh_b, em_b, lm_b,
        b_l0, b_l1, b_s3, WhT_l0f, WhT_l0b, WhT_l1f, WhT_l1b);

    // 1. layer-0 input projections, fused fwd+bwd (K=125, N=1000)
    proj_t<<<BT/MT, 512, 0, stream>>>(words, WT_l0, b_l0, A, 1000, D, D);

    // 2. layer-0 scan -> h0 (C)
    lstm_scan<<<B*2, 1024, 0, stream>>>(A, WhT_l0f, WhT_l0b, C);

    // 3. layer-1 input projections (K=250, N=1000)
    proj_t<<<BT/MT, 512, 0, stream>>>(C, WT_l1, b_l1, A, 1000, H2, H2);

    // 4. layer-1 scan -> ex (C, overwrites h0)
    lstm_scan<<<B*2, 1024, 0, stream>>>(A, WhT_l1f, WhT_l1b, C);

    // 5. fused scorer projections: s3 (eh+em+lm, N=300) + lh gathered (N=100)
    proj_s3lh<<<512, 256, 0, stream>>>(C, WT_s3, b_s3, A,
                                       WT_lh, lh_b, rel_head, target_arcs);

    // 6. fused arc + rel scoring/argmax
    arc_rel<<<1024 + BT, 128, 0, stream>>>(A, es_W, es_b, target_arcs, rel_head,
                                           ls_W, ls_b, arc_out, trees_out,
                                           rel_out, preds_out);
}